// Round 1
// baseline (561.241 us; speedup 1.0000x reference)
//
#include <hip/hip_runtime.h>
#include <hip/hip_bf16.h>

#define N_TOKENS 65536
#define MAXF 512
#define OUTF 1024

typedef __attribute__((ext_vector_type(8))) short short8;   // 8 bf16 (4 VGPRs)
typedef __attribute__((ext_vector_type(4))) float floatx4;

__device__ __forceinline__ unsigned short f2bf(float f) {
    unsigned int u = __float_as_uint(f);
    u += 0x7fffu + ((u >> 16) & 1u);   // round-to-nearest-even
    return (unsigned short)(u >> 16);
}

// ---- bucket tokens by group (wave-aggregated atomics) ----
__global__ void bucket_kernel(const int* __restrict__ sizes,
                              int* __restrict__ counts,
                              int* __restrict__ lists) {
    int i = blockIdx.x * 256 + threadIdx.x;
    if (i >= N_TOKENS) return;
    int lane = threadIdx.x & 63;
    int s = sizes[i];
    int g = (s == 64) ? 0 : (s == 128) ? 1 : (s == 256) ? 2 : 3;
    int slot = 0;
    #pragma unroll
    for (int gg = 0; gg < 4; ++gg) {
        unsigned long long m = __ballot(g == gg);
        if (g == gg) {
            int leader = __ffsll((unsigned long long)m) - 1;
            int cnt = __popcll(m);
            int base = 0;
            if (lane == leader) base = atomicAdd(&counts[gg], cnt);
            base = __shfl(base, leader);
            slot = base + __popcll(m & ((1ull << lane) - 1ull));
        }
    }
    lists[g * N_TOKENS + slot] = i;
}

// ---- grouped GEMM: out[idx[m], n] = sum_k x[idx[m],k] * w[g][n][k] + bias[g][n] ----
// 128x128 tile, BK=32, 4 waves (2x2 of 64x64), mfma_f32_16x16x32_bf16
__global__ __launch_bounds__(256) void gemm_kernel(
    const float* __restrict__ x, const float* __restrict__ weight,
    const float* __restrict__ bias, const int* __restrict__ counts,
    const int* __restrict__ lists, float* __restrict__ out) {

    const int g = blockIdx.z;
    const int count = counts[g];
    const int m_base = blockIdx.y * 128;
    if (m_base >= count) return;
    const int n_base = blockIdx.x * 128;
    const int K = 64 << g;
    const int rows = min(128, count - m_base);

    __shared__ unsigned short As[128][40];   // padded: 2-way bank alias only (free)
    __shared__ unsigned short Bs[128][40];
    __shared__ int idxs[128];

    const int t = threadIdx.x;
    if (t < 128) idxs[t] = (t < rows) ? lists[g * N_TOKENS + m_base + t] : 0;
    __syncthreads();

    const int wave = t >> 6, lane = t & 63;
    const int wm = wave >> 1, wn = wave & 1;
    const int quad = lane >> 4, l16 = lane & 15;

    floatx4 acc[4][4];
    #pragma unroll
    for (int i = 0; i < 4; ++i)
        #pragma unroll
        for (int j = 0; j < 4; ++j) acc[i][j] = (floatx4)(0.0f);

    const float* wg = weight + (size_t)g * OUTF * MAXF;

    for (int k0 = 0; k0 < K; k0 += 32) {
        // stage A and B tiles: 128 rows x 32 k, fp32 -> bf16 into LDS
        #pragma unroll
        for (int rep = 0; rep < 4; ++rep) {
            int id = t + rep * 256;      // 0..1023
            int row = id >> 3;           // 0..127
            int kq = id & 7;             // float4 index within 32-k chunk
            const float* ap = x + (size_t)idxs[row] * MAXF + k0 + kq * 4;
            floatx4 av = *(const floatx4*)ap;
            unsigned long long pa =
                (unsigned long long)f2bf(av[0]) |
                ((unsigned long long)f2bf(av[1]) << 16) |
                ((unsigned long long)f2bf(av[2]) << 32) |
                ((unsigned long long)f2bf(av[3]) << 48);
            *(unsigned long long*)&As[row][kq * 4] = pa;

            const float* bp = wg + (size_t)(n_base + row) * MAXF + k0 + kq * 4;
            floatx4 bv = *(const floatx4*)bp;
            unsigned long long pb =
                (unsigned long long)f2bf(bv[0]) |
                ((unsigned long long)f2bf(bv[1]) << 16) |
                ((unsigned long long)f2bf(bv[2]) << 32) |
                ((unsigned long long)f2bf(bv[3]) << 48);
            *(unsigned long long*)&Bs[row][kq * 4] = pb;
        }
        __syncthreads();

        short8 af[4], bfr[4];
        #pragma unroll
        for (int mi = 0; mi < 4; ++mi)
            af[mi] = *(const short8*)&As[wm * 64 + mi * 16 + l16][quad * 8];
        #pragma unroll
        for (int ni = 0; ni < 4; ++ni)
            bfr[ni] = *(const short8*)&Bs[wn * 64 + ni * 16 + l16][quad * 8];

        #pragma unroll
        for (int mi = 0; mi < 4; ++mi)
            #pragma unroll
            for (int ni = 0; ni < 4; ++ni)
                acc[mi][ni] = __builtin_amdgcn_mfma_f32_16x16x32_bf16(
                    af[mi], bfr[ni], acc[mi][ni], 0, 0, 0);
        __syncthreads();
    }

    // epilogue: C/D layout row=(lane>>4)*4+reg, col=lane&15
    #pragma unroll
    for (int ni = 0; ni < 4; ++ni) {
        int col = n_base + wn * 64 + ni * 16 + l16;
        float bv = bias[g * OUTF + col];
        #pragma unroll
        for (int mi = 0; mi < 4; ++mi) {
            int mloc = wm * 64 + mi * 16 + quad * 4;
            #pragma unroll
            for (int r = 0; r < 4; ++r) {
                int m = mloc + r;
                if (m < rows) {
                    out[(size_t)idxs[m] * OUTF + col] = acc[mi][ni][r] + bv;
                }
            }
        }
    }
}

extern "C" void kernel_launch(void* const* d_in, const int* in_sizes, int n_in,
                              void* d_out, int out_size, void* d_ws, size_t ws_size,
                              hipStream_t stream) {
    const float* x      = (const float*)d_in[0];
    const int*   sizes  = (const int*)d_in[1];
    const float* weight = (const float*)d_in[2];
    const float* bias   = (const float*)d_in[3];
    float* out = (float*)d_out;

    int* counts = (int*)d_ws;                 // 4 ints
    int* lists  = (int*)d_ws + 16;            // 64B offset; 4 * 65536 ints

    hipMemsetAsync(d_ws, 0, 64, stream);
    bucket_kernel<<<N_TOKENS / 256, 256, 0, stream>>>(sizes, counts, lists);

    dim3 grid(OUTF / 128, N_TOKENS / 128, 4);
    gemm_kernel<<<grid, 256, 0, stream>>>(x, weight, bias, counts, lists, out);
}

// Round 2
// 490.807 us; speedup vs baseline: 1.1435x; 1.1435x over previous
//
#include <hip/hip_runtime.h>
#include <hip/hip_bf16.h>

#define N_TOKENS 65536
#define MAXF 512
#define OUTF 1024
#define NGROUP 4

typedef __attribute__((ext_vector_type(8))) short short8;   // 8 bf16 (4 VGPRs)
typedef __attribute__((ext_vector_type(4))) float floatx4;
typedef unsigned short ushort_t;
typedef unsigned int uint_t;

__device__ __forceinline__ uint_t f2bf(float f) {
    uint_t u = __float_as_uint(f);
    u += 0x7fffu + ((u >> 16) & 1u);   // RNE
    return u >> 16;
}

// ws layout (bytes):
//   bases:      0      (8 ints: group starts, bases[4]=65536)
//   blockHist:  4096   (256*4 ints)
//   blockStart: 8192   (256*4 ints)
//   lists:      16384  (65536 ints, compact group-sorted token ids)
//   xb:         1MiB   (65536*512 bf16, compact group-sorted rows; K-prefix valid)
//   wb:         1MiB+64MiB (4*1024*512 bf16)
#define OFF_BASES  0
#define OFF_BHIST  4096
#define OFF_BSTART 8192
#define OFF_LISTS  16384
#define OFF_XB     (1u<<20)
#define OFF_WB     ((1u<<20) + ((size_t)N_TOKENS*MAXF*2))
#define WS_FULL    (OFF_WB + (size_t)NGROUP*OUTF*MAXF*2)
#define WS_MIN     (OFF_LISTS + (size_t)N_TOKENS*4)

// ---------- phase 1: per-block histogram (no atomics) ----------
__global__ void hist_kernel(const int* __restrict__ sizes, int* __restrict__ blockHist) {
    __shared__ int h[4][NGROUP];
    int t = threadIdx.x, wave = t >> 6;
    int tok = blockIdx.x * 256 + t;
    int g = __ffs(sizes[tok]) - 7;     // 64->0,128->1,256->2,512->3
    #pragma unroll
    for (int gg = 0; gg < NGROUP; ++gg) {
        unsigned long long m = __ballot(g == gg);
        if ((t & 63) == 0) h[wave][gg] = __popcll(m);
    }
    __syncthreads();
    if (t < NGROUP)
        blockHist[blockIdx.x * NGROUP + t] = h[0][t] + h[1][t] + h[2][t] + h[3][t];
}

// ---------- phase 2: scan over 256 blocks x 4 groups (single block) ----------
__global__ void scan_kernel(const int* __restrict__ blockHist,
                            int* __restrict__ blockStart, int* __restrict__ bases) {
    __shared__ int4 sh[256];
    int t = threadIdx.x;
    int4 v = ((const int4*)blockHist)[t];
    sh[t] = v;
    __syncthreads();
    for (int d = 1; d < 256; d <<= 1) {
        int4 u = sh[t];
        int4 a = make_int4(0, 0, 0, 0);
        if (t >= d) a = sh[t - d];
        __syncthreads();
        u.x += a.x; u.y += a.y; u.z += a.z; u.w += a.w;
        sh[t] = u;
        __syncthreads();
    }
    int4 incl = sh[t];
    int4 tot = sh[255];
    int b0 = 0, b1 = tot.x, b2 = b1 + tot.y, b3 = b2 + tot.z, b4 = b3 + tot.w;
    blockStart[t * 4 + 0] = b0 + incl.x - v.x;
    blockStart[t * 4 + 1] = b1 + incl.y - v.y;
    blockStart[t * 4 + 2] = b2 + incl.z - v.z;
    blockStart[t * 4 + 3] = b3 + incl.w - v.w;
    if (t == 0) {
        bases[0] = b0; bases[1] = b1; bases[2] = b2; bases[3] = b3; bases[4] = b4;
    }
}

// ---------- phase 3: scatter token ids into compact lists (no atomics) ----------
__global__ void scatter_kernel(const int* __restrict__ sizes,
                               const int* __restrict__ blockStart,
                               int* __restrict__ lists) {
    __shared__ int wcnt[4][NGROUP];
    int t = threadIdx.x, wave = t >> 6, lane = t & 63;
    int tok = blockIdx.x * 256 + t;
    int g = __ffs(sizes[tok]) - 7;
    int pos = 0;
    #pragma unroll
    for (int gg = 0; gg < NGROUP; ++gg) {
        unsigned long long m = __ballot(g == gg);
        if (g == gg) pos = __popcll(m & ((1ull << lane) - 1ull));
        if (lane == 0) wcnt[wave][gg] = __popcll(m);
    }
    __syncthreads();
    int off = blockStart[blockIdx.x * 4 + g];
    for (int w = 0; w < wave; ++w) off += wcnt[w][g];
    lists[off + pos] = tok;
}

// ---------- convert+compact x -> bf16 (one wave per slot) ----------
__global__ void convx_kernel(const float* __restrict__ x, const int* __restrict__ bases,
                             const int* __restrict__ lists, ushort_t* __restrict__ xb) {
    int slot = blockIdx.x * 4 + (threadIdx.x >> 6);
    int lane = threadIdx.x & 63;
    int b1 = bases[1], b2 = bases[2], b3 = bases[3];
    int g = (slot >= b3) ? 3 : (slot >= b2) ? 2 : (slot >= b1) ? 1 : 0;
    int K = 64 << g;
    int tok = lists[slot];
    const float2* src = (const float2*)(x + (size_t)tok * MAXF);
    uint_t* dst = (uint_t*)(xb + (size_t)slot * MAXF);
    for (int j = lane; j * 2 < K; j += 64) {
        float2 v = src[j];
        dst[j] = f2bf(v.x) | (f2bf(v.y) << 16);
    }
}

// ---------- convert weight -> bf16 ----------
__global__ void convw_kernel(const float* __restrict__ weight, ushort_t* __restrict__ wb) {
    int id = blockIdx.x * 256 + threadIdx.x;         // float4 units
    floatx4 v = ((const floatx4*)weight)[id];
    unsigned long long p = (unsigned long long)f2bf(v[0]) |
                           ((unsigned long long)f2bf(v[1]) << 16) |
                           ((unsigned long long)f2bf(v[2]) << 32) |
                           ((unsigned long long)f2bf(v[3]) << 48);
    ((unsigned long long*)wb)[id] = p;
}

#define GLOAD_LDS16(gptr, lptr)                                                \
    __builtin_amdgcn_global_load_lds(                                          \
        (const __attribute__((address_space(1))) uint_t*)(gptr),               \
        (__attribute__((address_space(3))) uint_t*)(lptr), 16, 0, 0)

// ---------- bf16 grouped GEMM, compact A, global_load_lds staging ----------
__global__ __launch_bounds__(256) void gemm_bf16_kernel(
    const ushort_t* __restrict__ xb, const ushort_t* __restrict__ wb,
    const float* __restrict__ bias, const int* __restrict__ bases,
    const int* __restrict__ lists, float* __restrict__ out) {

    const int g = blockIdx.z;
    const int gbase = bases[g];
    const int count = bases[g + 1] - gbase;
    const int m_base = blockIdx.y * 128;
    if (m_base >= count) return;
    const int n_base = blockIdx.x * 128;
    const int K = 64 << g;
    const int rows = min(128, count - m_base);

    __shared__ ushort_t As[128 * 32];   // [row][k], 64B rows, no pad (global_load_lds)
    __shared__ ushort_t Bs[128 * 32];
    __shared__ int oidx[128];

    const int t = threadIdx.x;
    const int wave = t >> 6, lane = t & 63;
    const int wm = wave >> 1, wn = wave & 1;
    const int quad = lane >> 4, l16 = lane & 15;

    const int rsub = lane >> 2;          // 0..15: row within 16-row chunk
    const int ksub = (lane & 3) * 8;     // bf16 elem offset within 32-k row

    floatx4 acc[4][4];
    #pragma unroll
    for (int i = 0; i < 4; ++i)
        #pragma unroll
        for (int j = 0; j < 4; ++j) acc[i][j] = (floatx4)(0.0f);

    const ushort_t* wg = wb + (size_t)g * OUTF * MAXF;

    for (int k0 = 0; k0 < K; k0 += 32) {
        #pragma unroll
        for (int j = 0; j < 2; ++j) {
            int br = wave * 32 + j * 16;                       // base row of 16-row chunk
            int ga = min(gbase + m_base + br + rsub, N_TOKENS - 1);
            GLOAD_LDS16(xb + (size_t)ga * MAXF + k0 + ksub, &As[br * 32]);
            int gb = n_base + br + rsub;
            GLOAD_LDS16(wg + (size_t)gb * MAXF + k0 + ksub, &Bs[br * 32]);
        }
        __syncthreads();

        short8 af[4], bf[4];
        #pragma unroll
        for (int mi = 0; mi < 4; ++mi)
            af[mi] = *(const short8*)&As[(wm * 64 + mi * 16 + l16) * 32 + quad * 8];
        #pragma unroll
        for (int ni = 0; ni < 4; ++ni)
            bf[ni] = *(const short8*)&Bs[(wn * 64 + ni * 16 + l16) * 32 + quad * 8];

        #pragma unroll
        for (int mi = 0; mi < 4; ++mi)
            #pragma unroll
            for (int ni = 0; ni < 4; ++ni)
                acc[mi][ni] = __builtin_amdgcn_mfma_f32_16x16x32_bf16(
                    af[mi], bf[ni], acc[mi][ni], 0, 0, 0);
        __syncthreads();
    }

    if (t < 128) oidx[t] = (t < rows) ? lists[gbase + m_base + t] : 0;
    __syncthreads();

    #pragma unroll
    for (int ni = 0; ni < 4; ++ni) {
        int col = n_base + wn * 64 + ni * 16 + l16;
        float bv = bias[g * OUTF + col];
        #pragma unroll
        for (int mi = 0; mi < 4; ++mi) {
            int mloc = wm * 64 + mi * 16 + quad * 4;
            #pragma unroll
            for (int r = 0; r < 4; ++r) {
                int m = mloc + r;
                if (m < rows)
                    out[(size_t)oidx[m] * OUTF + col] = acc[mi][ni][r] + bv;
            }
        }
    }
}

// ---------- fallback: fp32 gather GEMM (round-1 style, flat lists) ----------
__global__ __launch_bounds__(256) void gemm_fp32_kernel(
    const float* __restrict__ x, const float* __restrict__ weight,
    const float* __restrict__ bias, const int* __restrict__ bases,
    const int* __restrict__ lists, float* __restrict__ out) {

    const int g = blockIdx.z;
    const int gbase = bases[g];
    const int count = bases[g + 1] - gbase;
    const int m_base = blockIdx.y * 128;
    if (m_base >= count) return;
    const int n_base = blockIdx.x * 128;
    const int K = 64 << g;
    const int rows = min(128, count - m_base);

    __shared__ ushort_t As[128][40];
    __shared__ ushort_t Bs[128][40];
    __shared__ int idxs[128];

    const int t = threadIdx.x;
    if (t < 128) idxs[t] = (t < rows) ? lists[gbase + m_base + t] : lists[gbase + m_base];
    __syncthreads();

    const int wave = t >> 6, lane = t & 63;
    const int wm = wave >> 1, wn = wave & 1;
    const int quad = lane >> 4, l16 = lane & 15;

    floatx4 acc[4][4];
    #pragma unroll
    for (int i = 0; i < 4; ++i)
        #pragma unroll
        for (int j = 0; j < 4; ++j) acc[i][j] = (floatx4)(0.0f);

    const float* wg = weight + (size_t)g * OUTF * MAXF;

    for (int k0 = 0; k0 < K; k0 += 32) {
        #pragma unroll
        for (int rep = 0; rep < 4; ++rep) {
            int id = t + rep * 256;
            int row = id >> 3;
            int kq = id & 7;
            floatx4 av = *(const floatx4*)(x + (size_t)idxs[row] * MAXF + k0 + kq * 4);
            unsigned long long pa = (unsigned long long)f2bf(av[0]) |
                ((unsigned long long)f2bf(av[1]) << 16) |
                ((unsigned long long)f2bf(av[2]) << 32) |
                ((unsigned long long)f2bf(av[3]) << 48);
            *(unsigned long long*)&As[row][kq * 4] = pa;
            floatx4 bv = *(const floatx4*)(wg + (size_t)(n_base + row) * MAXF + k0 + kq * 4);
            unsigned long long pb = (unsigned long long)f2bf(bv[0]) |
                ((unsigned long long)f2bf(bv[1]) << 16) |
                ((unsigned long long)f2bf(bv[2]) << 32) |
                ((unsigned long long)f2bf(bv[3]) << 48);
            *(unsigned long long*)&Bs[row][kq * 4] = pb;
        }
        __syncthreads();

        short8 af[4], bf[4];
        #pragma unroll
        for (int mi = 0; mi < 4; ++mi)
            af[mi] = *(const short8*)&As[wm * 64 + mi * 16 + l16][quad * 8];
        #pragma unroll
        for (int ni = 0; ni < 4; ++ni)
            bf[ni] = *(const short8*)&Bs[wn * 64 + ni * 16 + l16][quad * 8];
        #pragma unroll
        for (int mi = 0; mi < 4; ++mi)
            #pragma unroll
            for (int ni = 0; ni < 4; ++ni)
                acc[mi][ni] = __builtin_amdgcn_mfma_f32_16x16x32_bf16(
                    af[mi], bf[ni], acc[mi][ni], 0, 0, 0);
        __syncthreads();
    }

    #pragma unroll
    for (int ni = 0; ni < 4; ++ni) {
        int col = n_base + wn * 64 + ni * 16 + l16;
        float bv = bias[g * OUTF + col];
        #pragma unroll
        for (int mi = 0; mi < 4; ++mi) {
            int mloc = wm * 64 + mi * 16 + quad * 4;
            #pragma unroll
            for (int r = 0; r < 4; ++r) {
                int m = mloc + r;
                if (m < rows)
                    out[(size_t)idxs[m] * OUTF + col] = acc[mi][ni][r] + bv;
            }
        }
    }
}

extern "C" void kernel_launch(void* const* d_in, const int* in_sizes, int n_in,
                              void* d_out, int out_size, void* d_ws, size_t ws_size,
                              hipStream_t stream) {
    const float* x      = (const float*)d_in[0];
    const int*   sizes  = (const int*)d_in[1];
    const float* weight = (const float*)d_in[2];
    const float* bias   = (const float*)d_in[3];
    float* out = (float*)d_out;

    char* ws = (char*)d_ws;
    int* bases      = (int*)(ws + OFF_BASES);
    int* blockHist  = (int*)(ws + OFF_BHIST);
    int* blockStart = (int*)(ws + OFF_BSTART);
    int* lists      = (int*)(ws + OFF_LISTS);
    ushort_t* xb    = (ushort_t*)(ws + OFF_XB);
    ushort_t* wb    = (ushort_t*)(ws + OFF_WB);

    hist_kernel<<<N_TOKENS / 256, 256, 0, stream>>>(sizes, blockHist);
    scan_kernel<<<1, 256, 0, stream>>>(blockHist, blockStart, bases);
    scatter_kernel<<<N_TOKENS / 256, 256, 0, stream>>>(sizes, blockStart, lists);

    dim3 grid(OUTF / 128, N_TOKENS / 128, NGROUP);
    if (ws_size >= WS_FULL) {
        convw_kernel<<<(NGROUP * OUTF * MAXF / 4) / 256, 256, 0, stream>>>(weight, wb);
        convx_kernel<<<N_TOKENS / 4, 256, 0, stream>>>(x, bases, lists, xb);
        gemm_bf16_kernel<<<grid, 256, 0, stream>>>(xb, wb, bias, bases, lists, out);
    } else {
        gemm_fp32_kernel<<<grid, 256, 0, stream>>>(x, weight, bias, bases, lists, out);
    }
}